// Round 4
// baseline (117.931 us; speedup 1.0000x reference)
//
#include <hip/hip_runtime.h>

#define NQ 11
#define NL 3
#define S  2048
#define NB 8
#define NA 96
#define NF 64
#define PADW 100
#define WPB 4            // waves (nodes) per block
#define PPB (NA / WPB)   // partial blocks per batch = 24

typedef float v2f __attribute__((ext_vector_type(2)));

#if defined(__has_builtin)
#if __has_builtin(__builtin_amdgcn_permlane16_swap) && __has_builtin(__builtin_amdgcn_permlane32_swap)
#define USE_PLSWAP 1
#endif
#endif
#ifndef USE_PLSWAP
#define USE_PLSWAP 0
#endif

__device__ __forceinline__ float sigmoidf_(float x) { return 1.0f / (1.0f + expf(-x)); }

// uniform broadcast from a given lane (SGPR path) — verified prior session
__device__ __forceinline__ float rl_(float v, int srclane) {
    return __builtin_bit_cast(float, __builtin_amdgcn_readlane(__builtin_bit_cast(int, v), srclane));
}

// ---- xor-partner primitives -------------------------------------------------
// DPP for masks 1,2,8 — verified in the round-0 passing kernel (absmax 0.0).
template<int M> __device__ __forceinline__ float dpp_x(float x) {
    const int xi = __builtin_bit_cast(int, x);
    if constexpr (M == 1)
        return __builtin_bit_cast(float, __builtin_amdgcn_mov_dpp(xi, 0xB1, 0xF, 0xF, true));
    else if constexpr (M == 2)
        return __builtin_bit_cast(float, __builtin_amdgcn_mov_dpp(xi, 0x4E, 0xF, 0xF, true));
    else {
        static_assert(M == 8, "dpp_x: unsupported mask");
        return __builtin_bit_cast(float, __builtin_amdgcn_mov_dpp(xi, 0x128, 0xF, 0xF, true));
    }
}

// FAST candidates (probed at runtime before use):
//  M=4 : update_dpp pair — row_shl:4 writes banks 0,2 (dst[i]=src[i+4]);
//        row_shr:4 writes banks 1,3 (dst[i]=src[i-4]).
//  M=16/32 : permlane{16,32}_swap(x,x) -> {lo = x[l&~M], hi = x[l|M]} (assumed).
__device__ __forceinline__ float fast4_(float x) {
    const int xi = __builtin_bit_cast(int, x);
    int r = __builtin_amdgcn_update_dpp(xi, xi, 0x104, 0xF, 0x5, false); // row_shl:4 -> banks 0,2
    r     = __builtin_amdgcn_update_dpp(r,  xi, 0x114, 0xF, 0xA, false); // row_shr:4 -> banks 1,3
    return __builtin_bit_cast(float, r);
}
template<int M> __device__ __forceinline__ void lohi_fast(float x, float& lo, float& hi) {
#if USE_PLSWAP
    const unsigned xi = __builtin_bit_cast(unsigned, x);
    if constexpr (M == 16) {
        auto p = __builtin_amdgcn_permlane16_swap(xi, xi, false, false);
        lo = __builtin_bit_cast(float, p[0]); hi = __builtin_bit_cast(float, p[1]);
    } else {
        static_assert(M == 32, "lohi_fast: unsupported mask");
        auto p = __builtin_amdgcn_permlane32_swap(xi, xi, false, false);
        lo = __builtin_bit_cast(float, p[0]); hi = __builtin_bit_cast(float, p[1]);
    }
#else
    // no permlane builtins: fall back to the safe exchanges (probe then passes
    // trivially and FAST == SAFE).
    float pw;
    int lane_ = threadIdx.x & 63;
    if constexpr (M == 16)
        pw = __builtin_bit_cast(float, __builtin_amdgcn_ds_swizzle(__builtin_bit_cast(int, x), 0x401F));
    else
        pw = __shfl_xor(x, 32, 64);
    const bool b = (lane_ & M) != 0;
    lo = b ? pw : x;
    hi = b ? x : pw;
#endif
}

// partner x[lane^M] — FAST (probed) vs SAFE (round-0 verbatim primitives)
template<bool FAST, int M> __device__ __forceinline__ float pxf(float x, int lane) {
    if constexpr (M == 1 || M == 2 || M == 8) {
        (void)lane; return dpp_x<M>(x);
    } else if constexpr (M == 4) {
        if constexpr (FAST) { (void)lane; return fast4_(x); }
        else { (void)lane; return __builtin_bit_cast(float,
                 __builtin_amdgcn_ds_swizzle(__builtin_bit_cast(int, x), 0x101F)); }
    } else if constexpr (M == 16) {
        if constexpr (FAST) {
            float lo, hi; lohi_fast<16>(x, lo, hi);
            return ((lane >> 4) & 1) ? lo : hi;
        } else { (void)lane; return __builtin_bit_cast(float,
                 __builtin_amdgcn_ds_swizzle(__builtin_bit_cast(int, x), 0x401F)); }
    } else {
        static_assert(M == 32, "pxf: unsupported mask");
        if constexpr (FAST) {
            float lo, hi; lohi_fast<32>(x, lo, hi);
            return ((lane >> 5) & 1) ? lo : hi;
        } else { (void)lane; return __shfl_xor(x, 32, 64); }
    }
}
template<bool FAST, int M> __device__ __forceinline__ v2f pxv(v2f w, int lane) {
    v2f r; r.x = pxf<FAST, M>(w.x, lane); r.y = pxf<FAST, M>(w.y, lane); return r;
}

// ---- gate primitives on packed statevector w[16]: state = ((2j+c)<<6)|lane ----
// Bodies are verbatim round-0 (verified absmax 0.0); only the partner producer
// is templated.
template<bool FAST, int Q> __device__ __forceinline__ void rot_lane(v2f* w, float g00, float g01,
                                                                    float g10, float g11, int lane) {
    const int bit  = (lane >> Q) & 1;
    const float c1 = bit ? g11 : g00;   // own
    const float c0 = bit ? g10 : g01;   // partner
#pragma unroll
    for (int j = 0; j < 16; ++j) {
        v2f pw = pxv<FAST, (1 << Q)>(w[j], lane);
        w[j] = c1 * w[j] + c0 * pw;     // pk_mul + pk_fma
    }
}
__device__ __forceinline__ void rot_comp(v2f* w, float g00, float g01, float g10, float g11) {
    v2f ca; ca.x = g00; ca.y = g11;
    v2f cb; cb.x = g01; cb.y = g10;
#pragma unroll
    for (int j = 0; j < 16; ++j) {
        v2f sw; sw.x = w[j].y; sw.y = w[j].x;
        w[j] = ca * w[j] + cb * sw;
    }
}
template<int B> __device__ __forceinline__ void rot_reg(v2f* w, float g00, float g01,
                                                        float g10, float g11) {
#pragma unroll
    for (int t = 0; t < 8; ++t) {
        const int j0 = ((t >> B) << (B + 1)) | (t & ((1 << B) - 1));
        const int j1 = j0 | (1 << B);
        v2f a0 = w[j0], a1 = w[j1];
        w[j0] = g00 * a0 + g01 * a1;
        w[j1] = g10 * a0 + g11 * a1;
    }
}
template<bool FAST, int Q> __device__ __forceinline__ void ent_lane(v2f* w, float p, int lane) {
    const float pact = p * (float)((lane >> Q) & 1);
#pragma unroll
    for (int j = 0; j < 16; ++j) {
        v2f pw = pxv<FAST, (1 << (Q + 1))>(w[j], lane);
        w[j] = w[j] + pact * (pw - w[j]);
    }
}
__device__ __forceinline__ void ent_5(v2f* w, float p, int lane) {
    const float pact = p * (float)((lane >> 5) & 1);
#pragma unroll
    for (int j = 0; j < 16; ++j) {
        v2f sw; sw.x = w[j].y; sw.y = w[j].x;
        w[j] = w[j] + pact * (sw - w[j]);
    }
}
__device__ __forceinline__ void ent_6(v2f* w, float p) {
#pragma unroll
    for (int t = 0; t < 8; ++t) {
        const int j0 = 2 * t, j1 = 2 * t + 1;
        const float d = w[j1].y - w[j0].y;
        w[j0].y = fmaf(p, d, w[j0].y);
        w[j1].y = fmaf(-p, d, w[j1].y);
    }
}
template<int B> __device__ __forceinline__ void ent_reg(v2f* w, float p) {
#pragma unroll
    for (int t = 0; t < 4; ++t) {
        const int j0 = ((t >> B) << (B + 2)) | (1 << B) | (t & ((1 << B) - 1));
        const int j1 = j0 | (1 << (B + 1));
        v2f d = w[j1] - w[j0];
        w[j0] = w[j0] + p * d;
        w[j1] = w[j1] - p * d;
    }
}

// the full 63-gate chain, templated on exchange path
template<bool FAST> __device__ __forceinline__ void gates_run(v2f* w, float m00, float m01,
                                                              float m10, float m11, float pent,
                                                              int lane) {
#define GC(G) const int gi = gb + (G); \
    const float g00 = rl_(m00, gi), g01 = rl_(m01, gi), g10 = rl_(m10, gi), g11 = rl_(m11, gi)
#define ROTL(Q) { GC(Q); rot_lane<FAST, Q>(w, g00, g01, g10, g11, lane); }
#define ROTR(B) { GC((B) + 7); rot_reg<B>(w, g00, g01, g10, g11); }
#define ENTL(Q) { const float p = rl_(pent, eb + (Q)); ent_lane<FAST, Q>(w, p, lane); }
    for (int l = 0; l < NL; ++l) {
        const int gb = l * NQ;
        const int eb = l * (NQ - 1);
        ROTL(0) ROTL(1) ROTL(2) ROTL(3) ROTL(4) ROTL(5)
        { GC(6); rot_comp(w, g00, g01, g10, g11); }
        ROTR(0) ROTR(1) ROTR(2) ROTR(3)
        ENTL(0) ENTL(1) ENTL(2) ENTL(3) ENTL(4)
        { const float p = rl_(pent, eb + 5); ent_5(w, p, lane); }
        { const float p = rl_(pent, eb + 6); ent_6(w, p); }
        { const float p = rl_(pent, eb + 7); ent_reg<0>(w, p); }
        { const float p = rl_(pent, eb + 8); ent_reg<1>(w, p); }
        { const float p = rl_(pent, eb + 9); ent_reg<2>(w, p); }
    }
#undef GC
#undef ROTL
#undef ROTR
#undef ENTL
}

// One WAVE per node (192 blocks x 256 thr). Block reduces its 4 nodes in LDS,
// stores ONE partial per block. No atomics, no fences, 3 barriers total.
__global__ __launch_bounds__(256) void circuit_kernel(
    const float* __restrict__ nf,     // [NB*NA, NF]
    const float* __restrict__ W1,     // [64,100]
    const float* __restrict__ b1,     // [64]
    const float* __restrict__ W2,     // [11,64]
    const float* __restrict__ b2,     // [11]
    const float* __restrict__ rot,    // [NL,NQ,3]
    const float* __restrict__ ent,    // [NL,NQ-1]
    const float* __restrict__ pool_w, // [11]
    float* __restrict__ Rpart)        // [PPB*NB, S]
{
    __shared__ float W1s[64 * 65];    // stride-65 pad: 2-way bank alias (free)
    __shared__ float xs[WPB][64];
    __shared__ float psum[WPB][S];

    const int tid  = threadIdx.x;
    const int lane = tid & 63;
    const int wave = tid >> 6;
    const int node = blockIdx.x * WPB + wave;
    const int a    = node % NA;

    // ---- stage W1[:,0:64] into padded LDS + node features ----
    {
        const int r  = tid >> 2;
        const int c0 = (tid & 3) << 4;
        const float4* src = reinterpret_cast<const float4*>(W1 + r * PADW + c0);
        float* dst = &W1s[r * 65 + c0];
#pragma unroll
        for (int j = 0; j < 4; ++j) {
            const float4 vv = src[j];
            dst[4 * j + 0] = vv.x; dst[4 * j + 1] = vv.y;
            dst[4 * j + 2] = vv.z; dst[4 * j + 3] = vv.w;
        }
        xs[wave][lane] = nf[blockIdx.x * WPB * NF + tid];
    }

    // ---- probe the FAST exchange primitives on raw lane IDs (exact bit check);
    //      __all -> wave-uniform verdict. Probed while staging loads are in flight.
    bool okf;
    {
        const float idf = __builtin_bit_cast(float, lane);
        bool ok = (__builtin_bit_cast(int, fast4_(idf)) == (lane ^ 4));
        float lo, hi;
        lohi_fast<16>(idf, lo, hi);
        ok = ok && (__builtin_bit_cast(int, lo) == (lane & ~16))
                && (__builtin_bit_cast(int, hi) == (lane | 16));
        lohi_fast<32>(idf, lo, hi);
        ok = ok && (__builtin_bit_cast(int, lo) == (lane & ~32))
                && (__builtin_bit_cast(int, hi) == (lane | 32));
        okf = __all(ok);
    }
    __syncthreads();

    // ---- h = relu(x @ W1[:, :64]^T + b1) ----
    float h = b1[lane];
    {
        const float* wrow = &W1s[lane * 65];
        const float* xv   = xs[wave];
#pragma unroll
        for (int k = 0; k < 64; ++k) h = fmaf(wrow[k], xv[k], h);
    }
    h = fmaxf(h, 0.0f);

    // ---- f[q] = tanh(b2[q] + h @ W2[q,:]) via wave butterfly (round-0 exact) ----
    float fscal = 0.0f;
#pragma unroll
    for (int q = 0; q < NQ; ++q) {
        float t = h * W2[q * 64 + lane];
#pragma unroll
        for (int off = 32; off >= 1; off >>= 1) t += __shfl_xor(t, off, 64);
        if (lane == q) fscal = tanhf(t + b2[q]);
    }

    // ---- lane g<33 computes gate g's 2x2 matrix; lane e<30 the ent p ----
    const int qidx = lane < 11 ? lane : (lane < 22 ? lane - 11 : (lane < 33 ? lane - 22 : 0));
    const float fg = __shfl(fscal, qidx, 64);
    float m00 = 0.f, m01 = 0.f, m10 = 0.f, m11 = 0.f;
    if (lane < NL * NQ) {
        const float* r = rot + lane * 3;
        const float hx = 0.5f * r[0] * fg;
        const float hy = 0.5f * r[1] * fg;
        const float hz = 0.5f * r[2] * fg;
        const float cx = cosf(hx), sx = sinf(hx);
        const float cy = cosf(hy), sy = sinf(hy);
        const float cz = cosf(hz), sz = sinf(hz);
        m00 = cx * cy * cz; m01 = -sx * sy * sz;
        m10 = sx * sy * cz; m11 = cx * cy * sz;
    }
    float pent = 0.0f;
    if (lane < NL * (NQ - 1)) pent = sigmoidf_(ent[lane]);

    // ---- packed register statevector ----
    v2f w[16];
#pragma unroll
    for (int j = 0; j < 16; ++j) { w[j].x = 0.0f; w[j].y = 0.0f; }
    if (lane == 0) w[0].x = 1.0f;

    if (okf) gates_run<true >(w, m00, m01, m10, m11, pent, lane);
    else     gates_run<false>(w, m00, m01, m10, m11, pent, lane);

    // ---- weighted write into LDS, block reduction, ONE partial store ----
    const float wgt = sigmoidf_(pool_w[a % NQ]);
#pragma unroll
    for (int j = 0; j < 16; ++j) {
        psum[wave][((2 * j + 0) << 6) | lane] = wgt * w[j].x;
        psum[wave][((2 * j + 1) << 6) | lane] = wgt * w[j].y;
    }
    __syncthreads();
    {
        float* Rb = Rpart + (size_t)blockIdx.x * S;
        for (int s = tid; s < S; s += 256)
            Rb[s] = psum[0][s] + psum[1][s] + psum[2][s] + psum[3][s];
    }
}

// One block per batch (512 thr): sum 24 partials with float4 loads,
// phase sums, 22->256->128->64 MLP. (Round-0 verified version, bit-exact.)
__global__ __launch_bounds__(512) void pool_mlp_kernel(
    const float* __restrict__ Rpart,  // [NB*PPB, S]
    const float* __restrict__ msg,    // [NL,NQ,3]
    const float* __restrict__ Wo1, const float* __restrict__ bo1,
    const float* __restrict__ Wo2, const float* __restrict__ bo2,
    const float* __restrict__ Wo3, const float* __restrict__ bo3,
    float* __restrict__ out)          // [NB,64]
{
    __shared__ float Theta[NQ];
    __shared__ float red[3][8];
    __shared__ float rm_sh, im_sh;
    __shared__ float h1[256];
    __shared__ float h2[128];

    const int b   = blockIdx.x;
    const int tid = threadIdx.x;

    if (tid < NQ) {
        float t = 0.0f;
        for (int l = 0; l < NL; ++l)
#pragma unroll
            for (int c = 0; c < 3; ++c) t += msg[(l * NQ + tid) * 3 + c];
        Theta[tid] = t;
    }
    __syncthreads();

    // each thread owns one float4 (4 consecutive states): 512 * 4 = 2048
    float psq = 0.0f, pc = 0.0f, ps = 0.0f;
    {
        const float4* Pb = reinterpret_cast<const float4*>(Rpart + (size_t)b * PPB * S);
        float4 R; R.x = 0.f; R.y = 0.f; R.z = 0.f; R.w = 0.f;
#pragma unroll 6
        for (int j = 0; j < PPB; ++j) {
            const float4 v = Pb[j * (S / 4) + tid];
            R.x += v.x; R.y += v.y; R.z += v.z; R.w += v.w;
        }
        const int s0 = tid * 4;
        float phiH = 0.0f;
#pragma unroll
        for (int q = 2; q < NQ; ++q)
            if ((s0 >> q) & 1) phiH += Theta[q];
        const float t0 = Theta[0], t1 = Theta[1];
        const float ph0 = phiH, ph1 = phiH + t0, ph2 = phiH + t1, ph3 = phiH + t0 + t1;
        psq = R.x * R.x + R.y * R.y + R.z * R.z + R.w * R.w;
        pc  = R.x * cosf(ph0) + R.y * cosf(ph1) + R.z * cosf(ph2) + R.w * cosf(ph3);
        ps  = R.x * sinf(ph0) + R.y * sinf(ph1) + R.z * sinf(ph2) + R.w * sinf(ph3);
    }
#pragma unroll
    for (int off = 32; off >= 1; off >>= 1) {
        psq += __shfl_xor(psq, off, 64);
        pc  += __shfl_xor(pc,  off, 64);
        ps  += __shfl_xor(ps,  off, 64);
    }
    const int lane = tid & 63, wave = tid >> 6;
    if (lane == 0) { red[0][wave] = psq; red[1][wave] = pc; red[2][wave] = ps; }
    __syncthreads();
    if (tid == 0) {
        float sq = 0.f, sc = 0.f, ss = 0.f;
#pragma unroll
        for (int wv = 0; wv < 8; ++wv) { sq += red[0][wv]; sc += red[1][wv]; ss += red[2][wv]; }
        const float norm = fmaxf(sqrtf(sq), 1e-12f);
        rm_sh = sc / (float)S / norm;
        im_sh = ss / (float)S / norm;
    }
    __syncthreads();
    const float rm = rm_sh, im = im_sh;

    // h1[j] = relu(rm * sum(Wo1[j,0:11]) + im * sum(Wo1[j,11:22]) + bo1[j])
    if (tid < 256) {
        float s1 = 0.0f, s2 = 0.0f;
        const float* wrow = Wo1 + tid * (2 * NQ);
#pragma unroll
        for (int k = 0; k < NQ; ++k)       s1 += wrow[k];
#pragma unroll
        for (int k = NQ; k < 2 * NQ; ++k)  s2 += wrow[k];
        h1[tid] = fmaxf(rm * s1 + im * s2 + bo1[tid], 0.0f);
    }
    __syncthreads();
    if (tid < 128) {
        float acc = bo2[tid];
        const float* wrow = Wo2 + tid * 256;
        for (int k = 0; k < 256; ++k) acc += h1[k] * wrow[k];
        h2[tid] = fmaxf(acc, 0.0f);
    }
    __syncthreads();
    if (tid < 64) {
        float acc = bo3[tid];
        const float* wrow = Wo3 + tid * 128;
        for (int k = 0; k < 128; ++k) acc += h2[k] * wrow[k];
        out[b * 64 + tid] = acc;
    }
}

extern "C" void kernel_launch(void* const* d_in, const int* in_sizes, int n_in,
                              void* d_out, int out_size, void* d_ws, size_t ws_size,
                              hipStream_t stream) {
    const float* nf     = (const float*)d_in[0];
    // d_in[1] = edge_indices (unused by the math)
    const float* W1     = (const float*)d_in[2];
    const float* b1     = (const float*)d_in[3];
    const float* W2     = (const float*)d_in[4];
    const float* b2     = (const float*)d_in[5];
    const float* rot    = (const float*)d_in[6];
    const float* ent    = (const float*)d_in[7];
    const float* msg    = (const float*)d_in[8];
    const float* pool_w = (const float*)d_in[9];
    const float* Wo1    = (const float*)d_in[10];
    const float* bo1    = (const float*)d_in[11];
    const float* Wo2    = (const float*)d_in[12];
    const float* bo2    = (const float*)d_in[13];
    const float* Wo3    = (const float*)d_in[14];
    const float* bo3    = (const float*)d_in[15];

    float* Rpart = (float*)d_ws;     // [NB*PPB, S] block partials (plain stores)

    circuit_kernel<<<dim3(NB * NA / WPB), dim3(256), 0, stream>>>(
        nf, W1, b1, W2, b2, rot, ent, pool_w, Rpart);

    pool_mlp_kernel<<<dim3(NB), dim3(512), 0, stream>>>(
        Rpart, msg, Wo1, bo1, Wo2, bo2, Wo3, bo3, (float*)d_out);
}

// Round 5
// 112.718 us; speedup vs baseline: 1.0463x; 1.0463x over previous
//
#include <hip/hip_runtime.h>

#define NQ 11
#define NL 3
#define S  2048
#define NB 8
#define NA 96
#define NF 64
#define PADW 100
#define WPB 4            // waves (nodes) per block
#define PPB (NA / WPB)   // partial blocks per batch = 24

typedef float v2f __attribute__((ext_vector_type(2)));

#if defined(__has_builtin)
#if __has_builtin(__builtin_amdgcn_permlane16_swap) && __has_builtin(__builtin_amdgcn_permlane32_swap)
#define USE_PLSWAP 1
#endif
#endif
#ifndef USE_PLSWAP
#define USE_PLSWAP 0
#endif

__device__ __forceinline__ float sigmoidf_(float x) { return 1.0f / (1.0f + expf(-x)); }

// uniform broadcast from a given lane (SGPR path) — verified prior session
__device__ __forceinline__ float rl_(float v, int srclane) {
    return __builtin_bit_cast(float, __builtin_amdgcn_readlane(__builtin_bit_cast(int, v), srclane));
}

// ---- xor-partner primitives -------------------------------------------------
// DPP for masks 1,2,8 — verified in the round-0 passing kernel (absmax 0.0).
template<int M> __device__ __forceinline__ float dpp_x(float x) {
    const int xi = __builtin_bit_cast(int, x);
    if constexpr (M == 1)
        return __builtin_bit_cast(float, __builtin_amdgcn_mov_dpp(xi, 0xB1, 0xF, 0xF, true));
    else if constexpr (M == 2)
        return __builtin_bit_cast(float, __builtin_amdgcn_mov_dpp(xi, 0x4E, 0xF, 0xF, true));
    else {
        static_assert(M == 8, "dpp_x: unsupported mask");
        return __builtin_bit_cast(float, __builtin_amdgcn_mov_dpp(xi, 0x128, 0xF, 0xF, true));
    }
}

// FAST candidates (probed at runtime before use; round-4 run: probe PASSED):
//  M=4 : update_dpp pair — row_shl:4 writes banks 0,2 (dst[i]=src[i+4]);
//        row_shr:4 writes banks 1,3 (dst[i]=src[i-4]).
//  M=16/32 : permlane{16,32}_swap(x,x) -> {lo = x[l&~M], hi = x[l|M]}.
__device__ __forceinline__ float fast4_(float x) {
    const int xi = __builtin_bit_cast(int, x);
    int r = __builtin_amdgcn_update_dpp(xi, xi, 0x104, 0xF, 0x5, false); // row_shl:4 -> banks 0,2
    r     = __builtin_amdgcn_update_dpp(r,  xi, 0x114, 0xF, 0xA, false); // row_shr:4 -> banks 1,3
    return __builtin_bit_cast(float, r);
}
template<int M> __device__ __forceinline__ void lohi_fast(float x, float& lo, float& hi) {
#if USE_PLSWAP
    const unsigned xi = __builtin_bit_cast(unsigned, x);
    if constexpr (M == 16) {
        auto p = __builtin_amdgcn_permlane16_swap(xi, xi, false, false);
        lo = __builtin_bit_cast(float, p[0]); hi = __builtin_bit_cast(float, p[1]);
    } else {
        static_assert(M == 32, "lohi_fast: unsupported mask");
        auto p = __builtin_amdgcn_permlane32_swap(xi, xi, false, false);
        lo = __builtin_bit_cast(float, p[0]); hi = __builtin_bit_cast(float, p[1]);
    }
#else
    // no permlane builtins: fall back to the safe exchanges (probe then passes
    // trivially and FAST == SAFE).
    float pw;
    int lane_ = threadIdx.x & 63;
    if constexpr (M == 16)
        pw = __builtin_bit_cast(float, __builtin_amdgcn_ds_swizzle(__builtin_bit_cast(int, x), 0x401F));
    else
        pw = __shfl_xor(x, 32, 64);
    const bool b = (lane_ & M) != 0;
    lo = b ? pw : x;
    hi = b ? x : pw;
#endif
}

// partner x[lane^M] — FAST (probed) vs SAFE (round-0 verbatim primitives)
template<bool FAST, int M> __device__ __forceinline__ float pxf(float x, int lane) {
    if constexpr (M == 1 || M == 2 || M == 8) {
        (void)lane; return dpp_x<M>(x);
    } else if constexpr (M == 4) {
        if constexpr (FAST) { (void)lane; return fast4_(x); }
        else { (void)lane; return __builtin_bit_cast(float,
                 __builtin_amdgcn_ds_swizzle(__builtin_bit_cast(int, x), 0x101F)); }
    } else if constexpr (M == 16) {
        if constexpr (FAST) {
            float lo, hi; lohi_fast<16>(x, lo, hi);
            return ((lane >> 4) & 1) ? lo : hi;
        } else { (void)lane; return __builtin_bit_cast(float,
                 __builtin_amdgcn_ds_swizzle(__builtin_bit_cast(int, x), 0x401F)); }
    } else {
        static_assert(M == 32, "pxf: unsupported mask");
        if constexpr (FAST) {
            float lo, hi; lohi_fast<32>(x, lo, hi);
            return ((lane >> 5) & 1) ? lo : hi;
        } else { (void)lane; return __shfl_xor(x, 32, 64); }
    }
}
template<bool FAST, int M> __device__ __forceinline__ v2f pxv(v2f w, int lane) {
    v2f r; r.x = pxf<FAST, M>(w.x, lane); r.y = pxf<FAST, M>(w.y, lane); return r;
}

// ---- gate primitives on packed statevector w[16]: state = ((2j+c)<<6)|lane ----
// Bodies are verbatim round-0 (verified absmax 0.0); only the partner producer
// is templated.
template<bool FAST, int Q> __device__ __forceinline__ void rot_lane(v2f* w, float g00, float g01,
                                                                    float g10, float g11, int lane) {
    const int bit  = (lane >> Q) & 1;
    const float c1 = bit ? g11 : g00;   // own
    const float c0 = bit ? g10 : g01;   // partner
#pragma unroll
    for (int j = 0; j < 16; ++j) {
        v2f pw = pxv<FAST, (1 << Q)>(w[j], lane);
        w[j] = c1 * w[j] + c0 * pw;     // pk_mul + pk_fma
    }
}
__device__ __forceinline__ void rot_comp(v2f* w, float g00, float g01, float g10, float g11) {
    v2f ca; ca.x = g00; ca.y = g11;
    v2f cb; cb.x = g01; cb.y = g10;
#pragma unroll
    for (int j = 0; j < 16; ++j) {
        v2f sw; sw.x = w[j].y; sw.y = w[j].x;
        w[j] = ca * w[j] + cb * sw;
    }
}
template<int B> __device__ __forceinline__ void rot_reg(v2f* w, float g00, float g01,
                                                        float g10, float g11) {
#pragma unroll
    for (int t = 0; t < 8; ++t) {
        const int j0 = ((t >> B) << (B + 1)) | (t & ((1 << B) - 1));
        const int j1 = j0 | (1 << B);
        v2f a0 = w[j0], a1 = w[j1];
        w[j0] = g00 * a0 + g01 * a1;
        w[j1] = g10 * a0 + g11 * a1;
    }
}
template<bool FAST, int Q> __device__ __forceinline__ void ent_lane(v2f* w, float p, int lane) {
    const float pact = p * (float)((lane >> Q) & 1);
#pragma unroll
    for (int j = 0; j < 16; ++j) {
        v2f pw = pxv<FAST, (1 << (Q + 1))>(w[j], lane);
        w[j] = w[j] + pact * (pw - w[j]);
    }
}
__device__ __forceinline__ void ent_5(v2f* w, float p, int lane) {
    const float pact = p * (float)((lane >> 5) & 1);
#pragma unroll
    for (int j = 0; j < 16; ++j) {
        v2f sw; sw.x = w[j].y; sw.y = w[j].x;
        w[j] = w[j] + pact * (sw - w[j]);
    }
}
__device__ __forceinline__ void ent_6(v2f* w, float p) {
#pragma unroll
    for (int t = 0; t < 8; ++t) {
        const int j0 = 2 * t, j1 = 2 * t + 1;
        const float d = w[j1].y - w[j0].y;
        w[j0].y = fmaf(p, d, w[j0].y);
        w[j1].y = fmaf(-p, d, w[j1].y);
    }
}
template<int B> __device__ __forceinline__ void ent_reg(v2f* w, float p) {
#pragma unroll
    for (int t = 0; t < 4; ++t) {
        const int j0 = ((t >> B) << (B + 2)) | (1 << B) | (t & ((1 << B) - 1));
        const int j1 = j0 | (1 << (B + 1));
        v2f d = w[j1] - w[j0];
        w[j0] = w[j0] + p * d;
        w[j1] = w[j1] - p * d;
    }
}

// the full 63-gate chain, templated on exchange path.
// LAYER LOOP DELIBERATELY NOT UNROLLED: the fully-unrolled chain (~3x layer
// body, x2 instantiations) blows the 32KiB I-cache and the kernel becomes
// instruction-fetch bound (round-4 evidence: VALUBusy 9%, DS eliminated, yet
// ~38us for ~8k-cycle VALU work). Rolled: layer 1 cold, layers 2-3 warm.
template<bool FAST> __device__ __forceinline__ void gates_run(v2f* w, float m00, float m01,
                                                              float m10, float m11, float pent,
                                                              int lane) {
#define GC(G) const int gi = gb + (G); \
    const float g00 = rl_(m00, gi), g01 = rl_(m01, gi), g10 = rl_(m10, gi), g11 = rl_(m11, gi)
#define ROTL(Q) { GC(Q); rot_lane<FAST, Q>(w, g00, g01, g10, g11, lane); }
#define ROTR(B) { GC((B) + 7); rot_reg<B>(w, g00, g01, g10, g11); }
#define ENTL(Q) { const float p = rl_(pent, eb + (Q)); ent_lane<FAST, Q>(w, p, lane); }
#pragma clang loop unroll(disable)
    for (int l = 0; l < NL; ++l) {
        const int gb = l * NQ;
        const int eb = l * (NQ - 1);
        ROTL(0) ROTL(1) ROTL(2) ROTL(3) ROTL(4) ROTL(5)
        { GC(6); rot_comp(w, g00, g01, g10, g11); }
        ROTR(0) ROTR(1) ROTR(2) ROTR(3)
        ENTL(0) ENTL(1) ENTL(2) ENTL(3) ENTL(4)
        { const float p = rl_(pent, eb + 5); ent_5(w, p, lane); }
        { const float p = rl_(pent, eb + 6); ent_6(w, p); }
        { const float p = rl_(pent, eb + 7); ent_reg<0>(w, p); }
        { const float p = rl_(pent, eb + 8); ent_reg<1>(w, p); }
        { const float p = rl_(pent, eb + 9); ent_reg<2>(w, p); }
    }
#undef GC
#undef ROTL
#undef ROTR
#undef ENTL
}

// One WAVE per node (192 blocks x 256 thr). Block reduces its 4 nodes in LDS,
// stores ONE partial per block. No atomics, no fences, 3 barriers total.
__global__ __launch_bounds__(256) void circuit_kernel(
    const float* __restrict__ nf,     // [NB*NA, NF]
    const float* __restrict__ W1,     // [64,100]
    const float* __restrict__ b1,     // [64]
    const float* __restrict__ W2,     // [11,64]
    const float* __restrict__ b2,     // [11]
    const float* __restrict__ rot,    // [NL,NQ,3]
    const float* __restrict__ ent,    // [NL,NQ-1]
    const float* __restrict__ pool_w, // [11]
    float* __restrict__ Rpart)        // [PPB*NB, S]
{
    __shared__ float W1s[64 * 65];    // stride-65 pad: 2-way bank alias (free)
    __shared__ float xs[WPB][64];
    __shared__ float psum[WPB][S];

    const int tid  = threadIdx.x;
    const int lane = tid & 63;
    const int wave = tid >> 6;
    const int node = blockIdx.x * WPB + wave;
    const int a    = node % NA;

    // ---- stage W1[:,0:64] into padded LDS + node features ----
    {
        const int r  = tid >> 2;
        const int c0 = (tid & 3) << 4;
        const float4* src = reinterpret_cast<const float4*>(W1 + r * PADW + c0);
        float* dst = &W1s[r * 65 + c0];
#pragma unroll
        for (int j = 0; j < 4; ++j) {
            const float4 vv = src[j];
            dst[4 * j + 0] = vv.x; dst[4 * j + 1] = vv.y;
            dst[4 * j + 2] = vv.z; dst[4 * j + 3] = vv.w;
        }
        xs[wave][lane] = nf[blockIdx.x * WPB * NF + tid];
    }

    // ---- preload W2 rows / b2 (independent loads, all in flight at once;
    //      values and use-order identical to the per-q loads they replace) ----
    float w2v[NQ];
#pragma unroll
    for (int q = 0; q < NQ; ++q) w2v[q] = W2[q * 64 + lane];
    const float b2l = b2[lane < NQ ? lane : 0];

    // ---- probe the FAST exchange primitives on raw lane IDs (exact bit check);
    //      __all -> wave-uniform verdict. Probed while staging loads are in flight.
    bool okf;
    {
        const float idf = __builtin_bit_cast(float, lane);
        bool ok = (__builtin_bit_cast(int, fast4_(idf)) == (lane ^ 4));
        float lo, hi;
        lohi_fast<16>(idf, lo, hi);
        ok = ok && (__builtin_bit_cast(int, lo) == (lane & ~16))
                && (__builtin_bit_cast(int, hi) == (lane | 16));
        lohi_fast<32>(idf, lo, hi);
        ok = ok && (__builtin_bit_cast(int, lo) == (lane & ~32))
                && (__builtin_bit_cast(int, hi) == (lane | 32));
        okf = __all(ok);
    }
    __syncthreads();

    // ---- h = relu(x @ W1[:, :64]^T + b1) ----
    float h = b1[lane];
    {
        const float* wrow = &W1s[lane * 65];
        const float* xv   = xs[wave];
#pragma unroll
        for (int k = 0; k < 64; ++k) h = fmaf(wrow[k], xv[k], h);
    }
    h = fmaxf(h, 0.0f);

    // ---- f[q] = tanh(b2[q] + h @ W2[q,:]) via wave butterfly (round-0 exact) ----
    float fscal = 0.0f;
#pragma unroll
    for (int q = 0; q < NQ; ++q) {
        float t = h * w2v[q];
#pragma unroll
        for (int off = 32; off >= 1; off >>= 1) t += __shfl_xor(t, off, 64);
        if (lane == q) fscal = tanhf(t + b2l);
    }

    // ---- lane g<33 computes gate g's 2x2 matrix; lane e<30 the ent p ----
    const int qidx = lane < 11 ? lane : (lane < 22 ? lane - 11 : (lane < 33 ? lane - 22 : 0));
    const float fg = __shfl(fscal, qidx, 64);
    float m00 = 0.f, m01 = 0.f, m10 = 0.f, m11 = 0.f;
    if (lane < NL * NQ) {
        const float* r = rot + lane * 3;
        const float hx = 0.5f * r[0] * fg;
        const float hy = 0.5f * r[1] * fg;
        const float hz = 0.5f * r[2] * fg;
        const float cx = cosf(hx), sx = sinf(hx);
        const float cy = cosf(hy), sy = sinf(hy);
        const float cz = cosf(hz), sz = sinf(hz);
        m00 = cx * cy * cz; m01 = -sx * sy * sz;
        m10 = sx * sy * cz; m11 = cx * cy * sz;
    }
    float pent = 0.0f;
    if (lane < NL * (NQ - 1)) pent = sigmoidf_(ent[lane]);

    // ---- packed register statevector ----
    v2f w[16];
#pragma unroll
    for (int j = 0; j < 16; ++j) { w[j].x = 0.0f; w[j].y = 0.0f; }
    if (lane == 0) w[0].x = 1.0f;

    if (okf) gates_run<true >(w, m00, m01, m10, m11, pent, lane);
    else     gates_run<false>(w, m00, m01, m10, m11, pent, lane);

    // ---- weighted write into LDS, block reduction, ONE partial store ----
    const float wgt = sigmoidf_(pool_w[a % NQ]);
#pragma unroll
    for (int j = 0; j < 16; ++j) {
        psum[wave][((2 * j + 0) << 6) | lane] = wgt * w[j].x;
        psum[wave][((2 * j + 1) << 6) | lane] = wgt * w[j].y;
    }
    __syncthreads();
    {
        float* Rb = Rpart + (size_t)blockIdx.x * S;
        for (int s = tid; s < S; s += 256)
            Rb[s] = psum[0][s] + psum[1][s] + psum[2][s] + psum[3][s];
    }
}

// One block per batch (512 thr): sum 24 partials with float4 loads,
// phase sums, 22->256->128->64 MLP. (Round-0 verified version, bit-exact.)
__global__ __launch_bounds__(512) void pool_mlp_kernel(
    const float* __restrict__ Rpart,  // [NB*PPB, S]
    const float* __restrict__ msg,    // [NL,NQ,3]
    const float* __restrict__ Wo1, const float* __restrict__ bo1,
    const float* __restrict__ Wo2, const float* __restrict__ bo2,
    const float* __restrict__ Wo3, const float* __restrict__ bo3,
    float* __restrict__ out)          // [NB,64]
{
    __shared__ float Theta[NQ];
    __shared__ float red[3][8];
    __shared__ float rm_sh, im_sh;
    __shared__ float h1[256];
    __shared__ float h2[128];

    const int b   = blockIdx.x;
    const int tid = threadIdx.x;

    if (tid < NQ) {
        float t = 0.0f;
        for (int l = 0; l < NL; ++l)
#pragma unroll
            for (int c = 0; c < 3; ++c) t += msg[(l * NQ + tid) * 3 + c];
        Theta[tid] = t;
    }
    __syncthreads();

    // each thread owns one float4 (4 consecutive states): 512 * 4 = 2048
    float psq = 0.0f, pc = 0.0f, ps = 0.0f;
    {
        const float4* Pb = reinterpret_cast<const float4*>(Rpart + (size_t)b * PPB * S);
        float4 R; R.x = 0.f; R.y = 0.f; R.z = 0.f; R.w = 0.f;
#pragma unroll 6
        for (int j = 0; j < PPB; ++j) {
            const float4 v = Pb[j * (S / 4) + tid];
            R.x += v.x; R.y += v.y; R.z += v.z; R.w += v.w;
        }
        const int s0 = tid * 4;
        float phiH = 0.0f;
#pragma unroll
        for (int q = 2; q < NQ; ++q)
            if ((s0 >> q) & 1) phiH += Theta[q];
        const float t0 = Theta[0], t1 = Theta[1];
        const float ph0 = phiH, ph1 = phiH + t0, ph2 = phiH + t1, ph3 = phiH + t0 + t1;
        psq = R.x * R.x + R.y * R.y + R.z * R.z + R.w * R.w;
        pc  = R.x * cosf(ph0) + R.y * cosf(ph1) + R.z * cosf(ph2) + R.w * cosf(ph3);
        ps  = R.x * sinf(ph0) + R.y * sinf(ph1) + R.z * sinf(ph2) + R.w * sinf(ph3);
    }
#pragma unroll
    for (int off = 32; off >= 1; off >>= 1) {
        psq += __shfl_xor(psq, off, 64);
        pc  += __shfl_xor(pc,  off, 64);
        ps  += __shfl_xor(ps,  off, 64);
    }
    const int lane = tid & 63, wave = tid >> 6;
    if (lane == 0) { red[0][wave] = psq; red[1][wave] = pc; red[2][wave] = ps; }
    __syncthreads();
    if (tid == 0) {
        float sq = 0.f, sc = 0.f, ss = 0.f;
#pragma unroll
        for (int wv = 0; wv < 8; ++wv) { sq += red[0][wv]; sc += red[1][wv]; ss += red[2][wv]; }
        const float norm = fmaxf(sqrtf(sq), 1e-12f);
        rm_sh = sc / (float)S / norm;
        im_sh = ss / (float)S / norm;
    }
    __syncthreads();
    const float rm = rm_sh, im = im_sh;

    // h1[j] = relu(rm * sum(Wo1[j,0:11]) + im * sum(Wo1[j,11:22]) + bo1[j])
    if (tid < 256) {
        float s1 = 0.0f, s2 = 0.0f;
        const float* wrow = Wo1 + tid * (2 * NQ);
#pragma unroll
        for (int k = 0; k < NQ; ++k)       s1 += wrow[k];
#pragma unroll
        for (int k = NQ; k < 2 * NQ; ++k)  s2 += wrow[k];
        h1[tid] = fmaxf(rm * s1 + im * s2 + bo1[tid], 0.0f);
    }
    __syncthreads();
    if (tid < 128) {
        float acc = bo2[tid];
        const float* wrow = Wo2 + tid * 256;
        for (int k = 0; k < 256; ++k) acc += h1[k] * wrow[k];
        h2[tid] = fmaxf(acc, 0.0f);
    }
    __syncthreads();
    if (tid < 64) {
        float acc = bo3[tid];
        const float* wrow = Wo3 + tid * 128;
        for (int k = 0; k < 128; ++k) acc += h2[k] * wrow[k];
        out[b * 64 + tid] = acc;
    }
}

extern "C" void kernel_launch(void* const* d_in, const int* in_sizes, int n_in,
                              void* d_out, int out_size, void* d_ws, size_t ws_size,
                              hipStream_t stream) {
    const float* nf     = (const float*)d_in[0];
    // d_in[1] = edge_indices (unused by the math)
    const float* W1     = (const float*)d_in[2];
    const float* b1     = (const float*)d_in[3];
    const float* W2     = (const float*)d_in[4];
    const float* b2     = (const float*)d_in[5];
    const float* rot    = (const float*)d_in[6];
    const float* ent    = (const float*)d_in[7];
    const float* msg    = (const float*)d_in[8];
    const float* pool_w = (const float*)d_in[9];
    const float* Wo1    = (const float*)d_in[10];
    const float* bo1    = (const float*)d_in[11];
    const float* Wo2    = (const float*)d_in[12];
    const float* bo2    = (const float*)d_in[13];
    const float* Wo3    = (const float*)d_in[14];
    const float* bo3    = (const float*)d_in[15];

    float* Rpart = (float*)d_ws;     // [NB*PPB, S] block partials (plain stores)

    circuit_kernel<<<dim3(NB * NA / WPB), dim3(256), 0, stream>>>(
        nf, W1, b1, W2, b2, rot, ent, pool_w, Rpart);

    pool_mlp_kernel<<<dim3(NB), dim3(512), 0, stream>>>(
        Rpart, msg, Wo1, bo1, Wo2, bo2, Wo3, bo3, (float*)d_out);
}